// Round 7
// baseline (247.070 us; speedup 1.0000x reference)
//
#include <hip/hip_runtime.h>
#include <hip/hip_cooperative_groups.h>
#include <math.h>

namespace cg = cooperative_groups;

// ---------------------------------------------------------------------------
// NormalDistributionChecker1D, round 7 — cooperative fusion, defensively.
// r6's coop launch silently failed (out never written, no hang): prime
// suspect is the co-residency check (VGPR>128 -> <4 blocks/CU -> 1024-block
// coop launch rejected). Fixes:
//   1) __launch_bounds__(256,4): cap VGPR at 128 so 4 blocks/CU fit.
//   2) grid sized from hipOccupancyMaxActiveBlocksPerMultiprocessor (the
//      same oracle the coop check uses), capped at 1024; loops use gridDim.
//   3) check the launch result; on ANY failure fall back to the proven r5
//      4-kernel path (plain-store partials, no atomics).
// Phases (fused): sum/sumsq -> part1 | grid.sync | all blocks reduce part1
// -> S,B; 9-sigmoid soft CDF -> part2 | grid.sync | block 0: reduce + chi2 +
// softmax epilogue -> out. All cross-block reductions fixed-order fp64.
// ---------------------------------------------------------------------------

#if __has_builtin(__builtin_amdgcn_exp2f)
#define EXP2F(x) __builtin_amdgcn_exp2f(x)
#else
#define EXP2F(x) exp2f(x)
#endif
#if __has_builtin(__builtin_amdgcn_rcpf)
#define RCPF(x) __builtin_amdgcn_rcpf(x)
#else
#define RCPF(x) (1.0f / (x))
#endif

#define MAXBLK 1024  // partials sized for this; grid never exceeds it
#define NCU 256      // MI355X

static __device__ __forceinline__ double wave_reduce_d(double v) {
#pragma unroll
    for (int off = 32; off > 0; off >>= 1) v += __shfl_down(v, off);
    return v;
}

__device__ __forceinline__ float sig9_a(float a, float* acc) {
    constexpr float C0 = -184.888834f, C1 = -121.420293f, C2 = -75.655000f,
                    C3 = -36.550261f, C4 = 0.0f, C5 = 36.550261f,
                    C6 = 75.655000f, C7 = 121.420293f, C8 = 184.888834f;
    // exp2 saturation is exact: rcp(1+inf)=0, rcp(1+0)=1.
    acc[0] += RCPF(1.0f + EXP2F(a - C0));
    acc[1] += RCPF(1.0f + EXP2F(a - C1));
    acc[2] += RCPF(1.0f + EXP2F(a - C2));
    acc[3] += RCPF(1.0f + EXP2F(a - C3));
    acc[4] += RCPF(1.0f + EXP2F(a - C4));
    acc[5] += RCPF(1.0f + EXP2F(a - C5));
    acc[6] += RCPF(1.0f + EXP2F(a - C6));
    acc[7] += RCPF(1.0f + EXP2F(a - C7));
    acc[8] += RCPF(1.0f + EXP2F(a - C8));
    return a;
}

__device__ void epilogue(const double* cum, float* out, int n) {
    const double CRIT[9] = {14.683657, 12.242145, 10.656372, 9.413640, 8.342832,
                            7.357034,  6.393306,  5.380053,  4.168159};
    const double nd = (double)n;
    double actual[10];
    actual[0] = cum[0];
#pragma unroll
    for (int k = 1; k < 9; ++k) actual[k] = cum[k] - cum[k - 1];
    actual[9] = nd - cum[8];
    const double expected = nd * (double)0.1f;
    const double denom = expected + 1e-7;
    double chi2 = 0.0;
#pragma unroll
    for (int j = 0; j < 10; ++j) {
        double d = actual[j] - expected;
        chi2 += d * d / denom;
    }
    double dneg[9], m = -1e300;
#pragma unroll
    for (int k = 0; k < 9; ++k) {
        dneg[k] = -fabs(chi2 - CRIT[k]);
        if (dneg[k] > m) m = dneg[k];
    }
    double W = 0.0, PQ = 0.0;
#pragma unroll
    for (int k = 0; k < 9; ++k) {
        double w = exp(dneg[k] - m);
        W += w;
        PQ += w * (0.1 * (double)(k + 1));
    }
    double p = 1.0 - PQ / W;
    double excess = (chi2 - 14.683657) / 100.0;
    if (excess < 0.0) excess = 0.0;
    out[0] = (float)(p + excess);
}

// ======================= fused cooperative kernel ==========================
// ws layout (double): [0..2*MAXBLK) part1 | [2*MAXBLK..2*MAXBLK+9*MAXBLK) part2
__global__ __launch_bounds__(256, 4) void fused_kernel(const float* __restrict__ x,
                                                       double* __restrict__ ws,
                                                       float* __restrict__ out, int n) {
    cg::grid_group grid = cg::this_grid();
    double* __restrict__ part1 = ws;
    double* __restrict__ part2 = ws + 2 * MAXBLK;

    const int tx = threadIdx.x;
    const int bid = blockIdx.x;
    const int nblk = gridDim.x;
    const int tid = bid * 256 + tx;
    const int nthreads = nblk * 256;
    const int n4 = n >> 2;
    const float4* __restrict__ x4 = (const float4*)x;
    const int lane = tx & 63, wid = tx >> 6;

    __shared__ double sm[4][9];
    __shared__ float sSB[2];

    // ---- phase 1: sum / sumsq ----
    {
        float fs = 0.f, fss = 0.f;
        for (int i = tid; i < n4; i += nthreads) {
            float4 v = x4[i];
            fs += (v.x + v.y) + (v.z + v.w);
            fss = fmaf(v.x, v.x, fss); fss = fmaf(v.y, v.y, fss);
            fss = fmaf(v.z, v.z, fss); fss = fmaf(v.w, v.w, fss);
        }
        if (bid == 0 && tx == 0) {  // n%4 tail (empty at n=16.7M)
            for (int j = n4 << 2; j < n; ++j) {
                float v = x[j];
                fs += v;
                fss = fmaf(v, v, fss);
            }
        }
        double s = wave_reduce_d((double)fs);
        double ss = wave_reduce_d((double)fss);
        if (lane == 0) { sm[wid][0] = s; sm[wid][1] = ss; }
        __syncthreads();
        if (tx == 0) {
            part1[2 * bid] = (sm[0][0] + sm[1][0]) + (sm[2][0] + sm[3][0]);
            part1[2 * bid + 1] = (sm[0][1] + sm[1][1]) + (sm[2][1] + sm[3][1]);
        }
        __syncthreads();
    }

    grid.sync();

    // ---- phase 2a: every block reduces part1 -> S,B (identical result) ----
    {
        double s = 0.0, ss = 0.0;
        for (int b = tx; b < nblk; b += 256) {  // fixed order -> deterministic
            s += part1[2 * b];
            ss += part1[2 * b + 1];
        }
        double rs = wave_reduce_d(s);
        double rss = wave_reduce_d(ss);
        if (lane == 0) { sm[wid][0] = rs; sm[wid][1] = rss; }
        __syncthreads();
        if (tx == 0) {
            double ts = (sm[0][0] + sm[1][0]) + (sm[2][0] + sm[3][0]);
            double tss = (sm[0][1] + sm[1][1]) + (sm[2][1] + sm[3][1]);
            const double Ld = 144.26950408889634;  // 100 * log2(e)
            const double nd = (double)n;
            const double mean = ts / nd;
            const double var = (tss - ts * ts / nd) / (nd - 1.0);  // ddof=1
            const double inv_std = 1.0 / sqrt(var);
            sSB[0] = (float)(Ld * inv_std);
            sSB[1] = (float)(-Ld * inv_std * mean);
        }
        __syncthreads();
    }
    const float S = sSB[0], B = sSB[1];

    // ---- phase 2b: 9-sigmoid soft CDF ----
    {
        float acc[9];
#pragma unroll
        for (int k = 0; k < 9; ++k) acc[k] = 0.f;

        for (int i = tid; i < n4; i += nthreads) {  // same addrs as phase 1
            float4 v = x4[i];
            sig9_a(fmaf(v.x, S, B), acc);
            sig9_a(fmaf(v.y, S, B), acc);
            sig9_a(fmaf(v.z, S, B), acc);
            sig9_a(fmaf(v.w, S, B), acc);
        }
        if (bid == 0 && tx == 0) {  // n%4 tail (empty at n=16.7M)
            for (int jj = n4 << 2; jj < n; ++jj) sig9_a(fmaf(x[jj], S, B), acc);
        }

        __syncthreads();
#pragma unroll
        for (int k = 0; k < 9; ++k) {
            double r = wave_reduce_d((double)acc[k]);
            if (lane == 0) sm[wid][k] = r;
        }
        __syncthreads();
        if (tx < 9) {
            part2[9 * bid + tx] = (sm[0][tx] + sm[1][tx]) + (sm[2][tx] + sm[3][tx]);
        }
    }

    grid.sync();

    // ---- phase 3: block 0 reduce + epilogue ----
    if (bid == 0) {
        double acc[9];
#pragma unroll
        for (int k = 0; k < 9; ++k) acc[k] = 0.0;
        for (int b = tx; b < nblk; b += 256) {  // fixed order
#pragma unroll
            for (int k = 0; k < 9; ++k) acc[k] += part2[9 * b + k];
        }
        __syncthreads();
#pragma unroll
        for (int k = 0; k < 9; ++k) {
            double r = wave_reduce_d(acc[k]);
            if (lane == 0) sm[wid][k] = r;
        }
        __syncthreads();
        if (tx == 0) {
            double cum[9];
#pragma unroll
            for (int k = 0; k < 9; ++k)
                cum[k] = (sm[0][k] + sm[1][k]) + (sm[2][k] + sm[3][k]);
            epilogue(cum, out, n);
        }
    }
}

// ===================== r5 fallback kernels (proven) ========================
__global__ __launch_bounds__(256) void pass1_stats(const float* __restrict__ x,
                                                   double* __restrict__ part1, int n) {
    const int tx = threadIdx.x;
    const int tid = blockIdx.x * 256 + tx;
    const int nthreads = gridDim.x * 256;
    const int n4 = n >> 2;
    const float4* __restrict__ x4 = (const float4*)x;

    float fs = 0.f, fss = 0.f;
    for (int i = tid; i < n4; i += nthreads) {
        float4 v = x4[i];
        fs += (v.x + v.y) + (v.z + v.w);
        fss = fmaf(v.x, v.x, fss); fss = fmaf(v.y, v.y, fss);
        fss = fmaf(v.z, v.z, fss); fss = fmaf(v.w, v.w, fss);
    }
    if (blockIdx.x == 0 && tx == 0) {
        for (int j = n4 << 2; j < n; ++j) {
            float v = x[j];
            fs += v;
            fss = fmaf(v, v, fss);
        }
    }
    double s = wave_reduce_d((double)fs);
    double ss = wave_reduce_d((double)fss);
    __shared__ double sm[4][2];
    const int lane = tx & 63, wid = tx >> 6;
    if (lane == 0) { sm[wid][0] = s; sm[wid][1] = ss; }
    __syncthreads();
    if (tx == 0) {
        part1[2 * blockIdx.x] = (sm[0][0] + sm[1][0]) + (sm[2][0] + sm[3][0]);
        part1[2 * blockIdx.x + 1] = (sm[0][1] + sm[1][1]) + (sm[2][1] + sm[3][1]);
    }
}

__global__ __launch_bounds__(256) void reduce_stats(const double* __restrict__ part1,
                                                    float* __restrict__ sb, int n) {
    const int tx = threadIdx.x;
    double s = 0.0, ss = 0.0;
    for (int b = tx; b < MAXBLK; b += 256) {
        s += part1[2 * b];
        ss += part1[2 * b + 1];
    }
    double rs = wave_reduce_d(s);
    double rss = wave_reduce_d(ss);
    __shared__ double sm[4][2];
    const int lane = tx & 63, wid = tx >> 6;
    if (lane == 0) { sm[wid][0] = rs; sm[wid][1] = rss; }
    __syncthreads();
    if (tx == 0) {
        double ts = (sm[0][0] + sm[1][0]) + (sm[2][0] + sm[3][0]);
        double tss = (sm[0][1] + sm[1][1]) + (sm[2][1] + sm[3][1]);
        const double Ld = 144.26950408889634;
        const double nd = (double)n;
        const double mean = ts / nd;
        const double var = (tss - ts * ts / nd) / (nd - 1.0);
        const double inv_std = 1.0 / sqrt(var);
        sb[0] = (float)(Ld * inv_std);
        sb[1] = (float)(-Ld * inv_std * mean);
    }
}

__global__ __launch_bounds__(256) void pass2_cum(const float* __restrict__ x,
                                                 const float* __restrict__ sb,
                                                 double* __restrict__ part2, int n) {
    const float S = sb[0], B = sb[1];
    float acc[9];
#pragma unroll
    for (int k = 0; k < 9; ++k) acc[k] = 0.f;

    const int tx = threadIdx.x;
    const int tid = blockIdx.x * 256 + tx;
    const int nthreads = gridDim.x * 256;
    const int n4 = n >> 2;
    const float4* __restrict__ x4 = (const float4*)x;

    for (int i = tid; i < n4; i += nthreads) {
        float4 v = x4[i];
        sig9_a(fmaf(v.x, S, B), acc);
        sig9_a(fmaf(v.y, S, B), acc);
        sig9_a(fmaf(v.z, S, B), acc);
        sig9_a(fmaf(v.w, S, B), acc);
    }
    if (blockIdx.x == 0 && tx == 0) {
        for (int jj = n4 << 2; jj < n; ++jj) sig9_a(fmaf(x[jj], S, B), acc);
    }

    __shared__ double sm[4][9];
    const int lane = tx & 63, wid = tx >> 6;
#pragma unroll
    for (int k = 0; k < 9; ++k) {
        double r = wave_reduce_d((double)acc[k]);
        if (lane == 0) sm[wid][k] = r;
    }
    __syncthreads();
    if (tx < 9) {
        part2[9 * blockIdx.x + tx] = (sm[0][tx] + sm[1][tx]) + (sm[2][tx] + sm[3][tx]);
    }
}

__global__ __launch_bounds__(256) void finalize_kernel(const double* __restrict__ part2,
                                                       float* __restrict__ out, int n) {
    const int tx = threadIdx.x;
    double acc[9];
#pragma unroll
    for (int k = 0; k < 9; ++k) acc[k] = 0.0;
    for (int b = tx; b < MAXBLK; b += 256) {
#pragma unroll
        for (int k = 0; k < 9; ++k) acc[k] += part2[9 * b + k];
    }
    __shared__ double sm[4][9];
    const int lane = tx & 63, wid = tx >> 6;
#pragma unroll
    for (int k = 0; k < 9; ++k) {
        double r = wave_reduce_d(acc[k]);
        if (lane == 0) sm[wid][k] = r;
    }
    __syncthreads();
    if (tx == 0) {
        double cum[9];
#pragma unroll
        for (int k = 0; k < 9; ++k)
            cum[k] = (sm[0][k] + sm[1][k]) + (sm[2][k] + sm[3][k]);
        epilogue(cum, out, n);
    }
}

extern "C" void kernel_launch(void* const* d_in, const int* in_sizes, int n_in,
                              void* d_out, int out_size, void* d_ws, size_t ws_size,
                              hipStream_t stream) {
    const float* x = (const float*)d_in[0];
    int n = in_sizes[0];
    double* ws = (double*)d_ws;
    float* out = (float*)d_out;

    // Size the coop grid from the runtime's own occupancy oracle so the
    // co-residency check cannot reject the launch.
    int per_cu = 0;
    hipError_t qerr = hipOccupancyMaxActiveBlocksPerMultiprocessor(
        &per_cu, (const void*)fused_kernel, 256, 0);
    if (qerr == hipSuccess && per_cu > 0) {
        int nblk = per_cu * NCU;
        if (nblk > MAXBLK) nblk = MAXBLK;
        void* args[] = {(void*)&x, (void*)&ws, (void*)&out, (void*)&n};
        hipError_t lerr = hipLaunchCooperativeKernel(
            (const void*)fused_kernel, dim3(nblk), dim3(256), args, 0, stream);
        if (lerr == hipSuccess) return;
    }

    // Fallback: proven r5 4-kernel path (no atomics, plain-store partials).
    double* part1 = ws;                      // 2*MAXBLK doubles
    double* part2 = ws + 2 * MAXBLK;         // 9*MAXBLK doubles
    float* sb = (float*)(part2 + 9 * MAXBLK);
    pass1_stats<<<MAXBLK, 256, 0, stream>>>(x, part1, n);
    reduce_stats<<<1, 256, 0, stream>>>(part1, sb, n);
    pass2_cum<<<MAXBLK, 256, 0, stream>>>(x, sb, part2, n);
    finalize_kernel<<<1, 256, 0, stream>>>(part2, out, n);
}

// Round 8
// 124.987 us; speedup vs baseline: 1.9768x; 1.9768x over previous
//
#include <hip/hip_runtime.h>
#include <math.h>

// ---------------------------------------------------------------------------
// NormalDistributionChecker1D, round 8 — r5 lineage (coop fusion was 190us of
// grid.sync spin; abandoned). Three kernels:
//   pass1_stats (1024 blk): sum/sumsq -> part1 (plain stores, no atomics)
//   pass2_cum   (1024 blk): inline fixed-order reduce of part1 -> S,B (each
//     block redundantly, 16KB L2 read), then HALF-EXP sigmoid soft CDF:
//       E = exp2(0.5*a); e_k = (E*2^(-C_k/2))^2; sigma_k = rcp(1+e_k)
//     -> 10 trans/elem (1 exp2 + 9 rcp) instead of 18. Saturation is exact:
//     E=inf -> t=inf -> sigma=0; E=0 -> t=0 -> sigma=1; t spans 2^+-197 and
//     fp32 over/underflow does the right thing, no clamp needed.
//   finalize (1 blk): reduce part2, chi2 + softmax epilogue.
// All cross-block reductions fixed-order fp64 -> deterministic across replays.
// ---------------------------------------------------------------------------

#if __has_builtin(__builtin_amdgcn_exp2f)
#define EXP2F(x) __builtin_amdgcn_exp2f(x)
#else
#define EXP2F(x) exp2f(x)
#endif
#if __has_builtin(__builtin_amdgcn_rcpf)
#define RCPF(x) __builtin_amdgcn_rcpf(x)
#else
#define RCPF(x) (1.0f / (x))
#endif

#define NBLK 1024  // 4 blocks/CU, 16 waves/CU

static __device__ __forceinline__ double wave_reduce_d(double v) {
#pragma unroll
    for (int off = 32; off > 0; off >>= 1) v += __shfl_down(v, off);
    return v;
}

// zscore thresholds (double, exact as in reference)
__device__ __constant__ double d_ZS[9] = {
    -1.2815516, -0.8416212, -0.5244005, -0.2533471, 0.0,
    0.2533471,  0.5244005,  0.8416212,  1.2815516};

__device__ void epilogue(const double* cum, float* out, int n) {
    const double CRIT[9] = {14.683657, 12.242145, 10.656372, 9.413640, 8.342832,
                            7.357034,  6.393306,  5.380053,  4.168159};
    const double nd = (double)n;
    double actual[10];
    actual[0] = cum[0];
#pragma unroll
    for (int k = 1; k < 9; ++k) actual[k] = cum[k] - cum[k - 1];
    actual[9] = nd - cum[8];
    const double expected = nd * (double)0.1f;
    const double denom = expected + 1e-7;
    double chi2 = 0.0;
#pragma unroll
    for (int j = 0; j < 10; ++j) {
        double d = actual[j] - expected;
        chi2 += d * d / denom;
    }
    double dneg[9], m = -1e300;
#pragma unroll
    for (int k = 0; k < 9; ++k) {
        dneg[k] = -fabs(chi2 - CRIT[k]);
        if (dneg[k] > m) m = dneg[k];
    }
    double W = 0.0, PQ = 0.0;
#pragma unroll
    for (int k = 0; k < 9; ++k) {
        double w = exp(dneg[k] - m);
        W += w;
        PQ += w * (0.1 * (double)(k + 1));
    }
    double p = 1.0 - PQ / W;
    double excess = (chi2 - 14.683657) / 100.0;
    if (excess < 0.0) excess = 0.0;
    out[0] = (float)(p + excess);
}

// ws layout (double): [0..2*NBLK) part1 | [2*NBLK..2*NBLK+9*NBLK) part2
__global__ __launch_bounds__(256) void pass1_stats(const float* __restrict__ x,
                                                   double* __restrict__ part1, int n) {
    const int tx = threadIdx.x;
    const int tid = blockIdx.x * 256 + tx;
    const int nthreads = NBLK * 256;
    const int n4 = n >> 2;
    const float4* __restrict__ x4 = (const float4*)x;

    float fs = 0.f, fss = 0.f;
    for (int i = tid; i < n4; i += nthreads) {  // 16 iters at n=16.7M
        float4 v = x4[i];
        fs += (v.x + v.y) + (v.z + v.w);
        fss = fmaf(v.x, v.x, fss); fss = fmaf(v.y, v.y, fss);
        fss = fmaf(v.z, v.z, fss); fss = fmaf(v.w, v.w, fss);
    }
    if (blockIdx.x == 0 && tx == 0) {  // n%4 scalar tail (empty at n=16.7M)
        for (int j = n4 << 2; j < n; ++j) {
            float v = x[j];
            fs += v;
            fss = fmaf(v, v, fss);
        }
    }
    double s = wave_reduce_d((double)fs);
    double ss = wave_reduce_d((double)fss);
    __shared__ double sm[4][2];
    const int lane = tx & 63, wid = tx >> 6;
    if (lane == 0) { sm[wid][0] = s; sm[wid][1] = ss; }
    __syncthreads();
    if (tx == 0) {
        part1[2 * blockIdx.x] = (sm[0][0] + sm[1][0]) + (sm[2][0] + sm[3][0]);
        part1[2 * blockIdx.x + 1] = (sm[0][1] + sm[1][1]) + (sm[2][1] + sm[3][1]);
    }
}

__global__ __launch_bounds__(256) void pass2_cum(const float* __restrict__ x,
                                                 const double* __restrict__ part1,
                                                 double* __restrict__ part2, int n) {
    const int tx = threadIdx.x;
    const int lane = tx & 63, wid = tx >> 6;

    // ---- inline stats reduce: every block computes identical S2,B2,sg[9] ----
    __shared__ double sm[4][9];
    __shared__ float sConst[11];  // [0]=S2 [1]=B2 [2..10]=sg[k]=2^(-C_k/2)
    {
        double s = 0.0, ss = 0.0;
        for (int b = tx; b < NBLK; b += 256) {  // fixed order -> deterministic
            s += part1[2 * b];
            ss += part1[2 * b + 1];
        }
        double rs = wave_reduce_d(s);
        double rss = wave_reduce_d(ss);
        if (lane == 0) { sm[wid][0] = rs; sm[wid][1] = rss; }
        __syncthreads();
        if (tx == 0) {
            double ts = (sm[0][0] + sm[1][0]) + (sm[2][0] + sm[3][0]);
            double tss = (sm[0][1] + sm[1][1]) + (sm[2][1] + sm[3][1]);
            const double Ld = 144.26950408889634;  // 100 * log2(e)
            const double nd = (double)n;
            const double mean = ts / nd;
            const double var = (tss - ts * ts / nd) / (nd - 1.0);  // ddof=1
            const double inv_std = 1.0 / sqrt(var);
            sConst[0] = (float)(0.5 * Ld * inv_std);          // S/2
            sConst[1] = (float)(-0.5 * Ld * inv_std * mean);  // B/2
#pragma unroll
            for (int k = 0; k < 9; ++k)
                sConst[2 + k] = (float)exp2(-0.5 * Ld * d_ZS[k]);  // 2^(-C_k/2)
        }
        __syncthreads();
    }
    const float S2 = sConst[0], B2 = sConst[1];
    float sg[9];
#pragma unroll
    for (int k = 0; k < 9; ++k) sg[k] = sConst[2 + k];

    float acc[9];
#pragma unroll
    for (int k = 0; k < 9; ++k) acc[k] = 0.f;

    auto process = [&](float xv) {
        const float E = EXP2F(fmaf(xv, S2, B2));  // 2^(a/2), a = 144.27*z
#pragma unroll
        for (int k = 0; k < 9; ++k) {
            const float t = E * sg[k];   // 2^((a-C_k)/2); over/underflow exact
            acc[k] += RCPF(1.0f + t * t);
        }
    };

    const int tid = blockIdx.x * 256 + tx;
    const int nthreads = NBLK * 256;
    const int n4 = n >> 2;
    const float4* __restrict__ x4 = (const float4*)x;

    for (int i = tid; i < n4; i += nthreads) {  // same mapping as pass1 -> L2
        float4 v = x4[i];
        process(v.x); process(v.y); process(v.z); process(v.w);
    }
    if (blockIdx.x == 0 && tx == 0) {  // n%4 scalar tail (empty at n=16.7M)
        for (int jj = n4 << 2; jj < n; ++jj) process(x[jj]);
    }

    __syncthreads();  // sm reuse
#pragma unroll
    for (int k = 0; k < 9; ++k) {
        double r = wave_reduce_d((double)acc[k]);
        if (lane == 0) sm[wid][k] = r;
    }
    __syncthreads();
    if (tx < 9) {
        part2[9 * blockIdx.x + tx] = (sm[0][tx] + sm[1][tx]) + (sm[2][tx] + sm[3][tx]);
    }
}

__global__ __launch_bounds__(256) void finalize_kernel(const double* __restrict__ part2,
                                                       float* __restrict__ out, int n) {
    const int tx = threadIdx.x;
    double acc[9];
#pragma unroll
    for (int k = 0; k < 9; ++k) acc[k] = 0.0;
    for (int b = tx; b < NBLK; b += 256) {  // fixed order -> deterministic
#pragma unroll
        for (int k = 0; k < 9; ++k) acc[k] += part2[9 * b + k];
    }
    __shared__ double sm[4][9];
    const int lane = tx & 63, wid = tx >> 6;
#pragma unroll
    for (int k = 0; k < 9; ++k) {
        double r = wave_reduce_d(acc[k]);
        if (lane == 0) sm[wid][k] = r;
    }
    __syncthreads();
    if (tx == 0) {
        double cum[9];
#pragma unroll
        for (int k = 0; k < 9; ++k)
            cum[k] = (sm[0][k] + sm[1][k]) + (sm[2][k] + sm[3][k]);
        epilogue(cum, out, n);
    }
}

extern "C" void kernel_launch(void* const* d_in, const int* in_sizes, int n_in,
                              void* d_out, int out_size, void* d_ws, size_t ws_size,
                              hipStream_t stream) {
    const float* x = (const float*)d_in[0];
    const int n = in_sizes[0];
    double* part1 = (double*)d_ws;       // 2*NBLK doubles
    double* part2 = part1 + 2 * NBLK;    // 9*NBLK doubles

    pass1_stats<<<NBLK, 256, 0, stream>>>(x, part1, n);
    pass2_cum<<<NBLK, 256, 0, stream>>>(x, part1, part2, n);
    finalize_kernel<<<1, 256, 0, stream>>>(part2, (float*)d_out, n);
}